// Round 13
// baseline (437.540 us; speedup 1.0000x reference)
//
#include <hip/hip_runtime.h>
#include <stdint.h>

// FeaturePropagator: 10 iters of out = mask ? x : (D^-1/2 A D^-1/2) @ out
// N=100000, E=1600000, D=64.
//
// Scaled-state: s_hat = D^-1/2 s => s_hat'[i] = dinv[i]^2 * sum_{row_e=i} s_hat[col_e];
// final out[i] = dinv[i] * sum. State bf16. CSR = slot array csr[r*CAP+k] (one
// fused atomic edge pass). SpMM: persistent waves over worklist; 8 groups x 8
// lanes; ALL 8 group-cols shfl'd at row start -> up to 8 gathers in flight
// (breaks the per-trip shfl->load chain); cross-row meta prefetch.

typedef unsigned short bf16_t;
typedef unsigned int u32;

__device__ __forceinline__ float bf2f(u32 u) {  // low 16 bits = bf16
  union { u32 i; float f; } v;
  v.i = u << 16;
  return v.f;
}
__device__ __forceinline__ u32 f2bf(float f) {  // RNE, returns low16
  union { float f; u32 i; } v;
  v.f = f;
  u32 u = v.i;
  return (u + 0x7FFFu + ((u >> 16) & 1u)) >> 16;
}

__device__ __forceinline__ bool mask_at(const void* m, int i, int byteFlag) {
  return byteFlag ? (((const uint8_t*)m)[i] != 0) : (((const int*)m)[i] != 0);
}

// Parallel detection: is mask 1-byte bool or 4-byte int32? One block.
__global__ void k_detect_mask(const uint8_t* m, int n, int* flag) {
  __shared__ int isByte, anyAligned;
  if (threadIdx.x == 0) { isByte = 0; anyAligned = 0; }
  __syncthreads();
  int nb = n < 4096 ? n : 4096;
  for (int i = threadIdx.x; i < nb; i += blockDim.x) {
    uint8_t v = m[i];
    if (v) {
      if (i & 3) atomicOr(&isByte, 1);
      else       atomicOr(&anyAligned, 1);
    }
  }
  __syncthreads();
  if (threadIdx.x == 0) *flag = (isByte || !anyAligned) ? 1 : 0;
}

// ONE pass over edges: in-degree over col + slot-scatter of unmasked-row edges.
__global__ void k_fused_preproc(const int* __restrict__ row, const int* __restrict__ col,
                                int E, const void* __restrict__ mask,
                                const int* __restrict__ flag, int CAP,
                                int* __restrict__ deg_col, int* __restrict__ cursor,
                                int* __restrict__ csr) {
  int e = blockIdx.x * blockDim.x + threadIdx.x;
  if (e >= E) return;
  int fl = *flag;
  int r = row[e], c = col[e];
  atomicAdd(&deg_col[c], 1);
  if (!mask_at(mask, r, fl)) {
    int pos = atomicAdd(&cursor[r], 1);
    if (pos < CAP) csr[r * CAP + pos] = c;  // overflow beyond CAP dropped (p ~ 1e-15 @64)
  }
}

// dinv + compacted worklist of unmasked rows (order nondeterministic; output
// order-independent since each row writes only its own dst slice).
__global__ void k_dinv_wlist(const int* __restrict__ deg_col, float* __restrict__ dinv,
                             const void* __restrict__ mask, const int* __restrict__ flag,
                             int* __restrict__ wlist, int* __restrict__ n_un, int N) {
  int i = blockIdx.x * blockDim.x + threadIdx.x;
  if (i >= N) return;
  int d = deg_col[i];
  dinv[i] = d > 0 ? rsqrtf((float)d) : 0.0f;
  if (!mask_at(mask, i, *flag)) {
    int pos = atomicAdd(n_un, 1);  // compiler wave-aggregates (same address)
    wlist[pos] = i;
  }
}

// Init: masked rows -> b0=b1=bf16(dinv*x) AND out=x (final value, never
// rewritten); unmasked rows -> b0=0 (iteration-0 state).
__global__ void k_init_state(const float* __restrict__ x, const float* __restrict__ dinv,
                             const void* __restrict__ mask, const int* __restrict__ flag,
                             bf16_t* __restrict__ b0, bf16_t* __restrict__ b1,
                             float* __restrict__ out, int total) {
  int i = blockIdx.x * blockDim.x + threadIdx.x;
  if (i >= total) return;
  int n = i >> 6;  // D == 64
  if (mask_at(mask, n, *flag)) {
    float xv = x[i];
    bf16_t v = (bf16_t)f2bf(dinv[n] * xv);
    b0[i] = v;
    b1[i] = v;
    out[i] = xv;
  } else {
    b0[i] = 0;
  }
}

// Row gather: all 8 trip-columns broadcast up front (independent shfls), then
// up to 8 conditional 16B gathers issued back-to-back (8-deep MLP), then
// unpack-accumulate and 3-round group reduction. Requires: lane,g,li,cnt,
// colv,src in scope. Produces reduced a0..a7 (valid in g==0 lanes).
#define GATHER8()                                                                  \
  float a0 = 0.f, a1 = 0.f, a2 = 0.f, a3 = 0.f,                                    \
        a4 = 0.f, a5 = 0.f, a6 = 0.f, a7 = 0.f;                                    \
  {                                                                                \
    int c0 = __shfl(colv, g, 64);                                                  \
    int c1 = __shfl(colv, 8 + g, 64);                                              \
    int c2 = __shfl(colv, 16 + g, 64);                                             \
    int c3 = __shfl(colv, 24 + g, 64);                                             \
    int c4 = __shfl(colv, 32 + g, 64);                                             \
    int c5 = __shfl(colv, 40 + g, 64);                                             \
    int c6 = __shfl(colv, 48 + g, 64);                                             \
    int c7 = __shfl(colv, 56 + g, 64);                                             \
    uint4 z = make_uint4(0, 0, 0, 0);                                              \
    uint4 v0 = z, v1 = z, v2 = z, v3 = z, v4 = z, v5 = z, v6 = z, v7 = z;          \
    if (g < cnt)      v0 = *(const uint4*)(src + (((size_t)c0) << 6) + (li << 3)); \
    if (8 + g < cnt)  v1 = *(const uint4*)(src + (((size_t)c1) << 6) + (li << 3)); \
    if (16 + g < cnt) v2 = *(const uint4*)(src + (((size_t)c2) << 6) + (li << 3)); \
    if (24 + g < cnt) v3 = *(const uint4*)(src + (((size_t)c3) << 6) + (li << 3)); \
    if (32 + g < cnt) v4 = *(const uint4*)(src + (((size_t)c4) << 6) + (li << 3)); \
    if (40 + g < cnt) v5 = *(const uint4*)(src + (((size_t)c5) << 6) + (li << 3)); \
    if (48 + g < cnt) v6 = *(const uint4*)(src + (((size_t)c6) << 6) + (li << 3)); \
    if (56 + g < cnt) v7 = *(const uint4*)(src + (((size_t)c7) << 6) + (li << 3)); \
    a0 = ((bf2f(v0.x & 0xffffu) + bf2f(v1.x & 0xffffu)) +                          \
          (bf2f(v2.x & 0xffffu) + bf2f(v3.x & 0xffffu))) +                         \
         ((bf2f(v4.x & 0xffffu) + bf2f(v5.x & 0xffffu)) +                          \
          (bf2f(v6.x & 0xffffu) + bf2f(v7.x & 0xffffu)));                          \
    a1 = ((bf2f(v0.x >> 16) + bf2f(v1.x >> 16)) +                                  \
          (bf2f(v2.x >> 16) + bf2f(v3.x >> 16))) +                                 \
         ((bf2f(v4.x >> 16) + bf2f(v5.x >> 16)) +                                  \
          (bf2f(v6.x >> 16) + bf2f(v7.x >> 16)));                                  \
    a2 = ((bf2f(v0.y & 0xffffu) + bf2f(v1.y & 0xffffu)) +                          \
          (bf2f(v2.y & 0xffffu) + bf2f(v3.y & 0xffffu))) +                         \
         ((bf2f(v4.y & 0xffffu) + bf2f(v5.y & 0xffffu)) +                          \
          (bf2f(v6.y & 0xffffu) + bf2f(v7.y & 0xffffu)));                          \
    a3 = ((bf2f(v0.y >> 16) + bf2f(v1.y >> 16)) +                                  \
          (bf2f(v2.y >> 16) + bf2f(v3.y >> 16))) +                                 \
         ((bf2f(v4.y >> 16) + bf2f(v5.y >> 16)) +                                  \
          (bf2f(v6.y >> 16) + bf2f(v7.y >> 16)));                                  \
    a4 = ((bf2f(v0.z & 0xffffu) + bf2f(v1.z & 0xffffu)) +                          \
          (bf2f(v2.z & 0xffffu) + bf2f(v3.z & 0xffffu))) +                         \
         ((bf2f(v4.z & 0xffffu) + bf2f(v5.z & 0xffffu)) +                          \
          (bf2f(v6.z & 0xffffu) + bf2f(v7.z & 0xffffu)));                          \
    a5 = ((bf2f(v0.z >> 16) + bf2f(v1.z >> 16)) +                                  \
          (bf2f(v2.z >> 16) + bf2f(v3.z >> 16))) +                                 \
         ((bf2f(v4.z >> 16) + bf2f(v5.z >> 16)) +                                  \
          (bf2f(v6.z >> 16) + bf2f(v7.z >> 16)));                                  \
    a6 = ((bf2f(v0.w & 0xffffu) + bf2f(v1.w & 0xffffu)) +                          \
          (bf2f(v2.w & 0xffffu) + bf2f(v3.w & 0xffffu))) +                         \
         ((bf2f(v4.w & 0xffffu) + bf2f(v5.w & 0xffffu)) +                          \
          (bf2f(v6.w & 0xffffu) + bf2f(v7.w & 0xffffu)));                          \
    a7 = ((bf2f(v0.w >> 16) + bf2f(v1.w >> 16)) +                                  \
          (bf2f(v2.w >> 16) + bf2f(v3.w >> 16))) +                                 \
         ((bf2f(v4.w >> 16) + bf2f(v5.w >> 16)) +                                  \
          (bf2f(v6.w >> 16) + bf2f(v7.w >> 16)));                                  \
  }                                                                                \
  a0 += __shfl_xor(a0, 8, 64); a0 += __shfl_xor(a0, 16, 64); a0 += __shfl_xor(a0, 32, 64); \
  a1 += __shfl_xor(a1, 8, 64); a1 += __shfl_xor(a1, 16, 64); a1 += __shfl_xor(a1, 32, 64); \
  a2 += __shfl_xor(a2, 8, 64); a2 += __shfl_xor(a2, 16, 64); a2 += __shfl_xor(a2, 32, 64); \
  a3 += __shfl_xor(a3, 8, 64); a3 += __shfl_xor(a3, 16, 64); a3 += __shfl_xor(a3, 32, 64); \
  a4 += __shfl_xor(a4, 8, 64); a4 += __shfl_xor(a4, 16, 64); a4 += __shfl_xor(a4, 32, 64); \
  a5 += __shfl_xor(a5, 8, 64); a5 += __shfl_xor(a5, 16, 64); a5 += __shfl_xor(a5, 32, 64); \
  a6 += __shfl_xor(a6, 8, 64); a6 += __shfl_xor(a6, 16, 64); a6 += __shfl_xor(a6, 32, 64); \
  a7 += __shfl_xor(a7, 8, 64); a7 += __shfl_xor(a7, 16, 64); a7 += __shfl_xor(a7, 32, 64);

// Persistent-wave SpMM (bf16 -> bf16).
__global__ void __launch_bounds__(256)
k_spmm_mid(const int* __restrict__ wlist, const int* __restrict__ n_un,
           const int* __restrict__ csr, const int* __restrict__ cursor, int CAP,
           const bf16_t* __restrict__ src, const float* __restrict__ dinv,
           bf16_t* __restrict__ dst) {
  int wpb = blockDim.x >> 6;
  int stride = gridDim.x * wpb;
  int lane = threadIdx.x & 63;
  int g = lane >> 3, li = lane & 7;
  int n = *n_un;
  int i = blockIdx.x * wpb + (threadIdx.x >> 6);
  if (i >= n) return;
  int rid = wlist[i];
  int cnt = cursor[rid]; if (cnt > CAP) cnt = CAP;
  int colv = (lane < cnt) ? csr[rid * CAP + lane] : 0;
  float di = dinv[rid];
  while (true) {
    int inext = i + stride;
    bool have_next = inext < n;
    int rid2 = 0, cnt2 = 0, colv2 = 0;
    float di2 = 0.f;
    if (have_next) {  // prefetch next row's meta under current row's gather
      rid2 = wlist[inext];
      cnt2 = cursor[rid2]; if (cnt2 > CAP) cnt2 = CAP;
      colv2 = (lane < cnt2) ? csr[rid2 * CAP + lane] : 0;
      di2 = dinv[rid2];
    }
    GATHER8()
    if (g == 0) {
      float s = di * di;
      uint4 o;
      o.x = f2bf(s * a0) | (f2bf(s * a1) << 16);
      o.y = f2bf(s * a2) | (f2bf(s * a3) << 16);
      o.z = f2bf(s * a4) | (f2bf(s * a5) << 16);
      o.w = f2bf(s * a6) | (f2bf(s * a7) << 16);
      *(uint4*)(dst + (((size_t)rid) << 6) + (li << 3)) = o;
    }
    if (!have_next) break;
    i = inext; rid = rid2; cnt = cnt2; colv = colv2; di = di2;
  }
}

// Final iteration: bf16 -> fp32 d_out with dinv unscaling (unmasked rows only;
// masked rows were written by k_init_state).
__global__ void __launch_bounds__(256)
k_spmm_fin(const int* __restrict__ wlist, const int* __restrict__ n_un,
           const int* __restrict__ csr, const int* __restrict__ cursor, int CAP,
           const bf16_t* __restrict__ src, const float* __restrict__ dinv,
           float* __restrict__ out) {
  int wpb = blockDim.x >> 6;
  int stride = gridDim.x * wpb;
  int lane = threadIdx.x & 63;
  int g = lane >> 3, li = lane & 7;
  int n = *n_un;
  int i = blockIdx.x * wpb + (threadIdx.x >> 6);
  if (i >= n) return;
  int rid = wlist[i];
  int cnt = cursor[rid]; if (cnt > CAP) cnt = CAP;
  int colv = (lane < cnt) ? csr[rid * CAP + lane] : 0;
  float di = dinv[rid];
  while (true) {
    int inext = i + stride;
    bool have_next = inext < n;
    int rid2 = 0, cnt2 = 0, colv2 = 0;
    float di2 = 0.f;
    if (have_next) {
      rid2 = wlist[inext];
      cnt2 = cursor[rid2]; if (cnt2 > CAP) cnt2 = CAP;
      colv2 = (lane < cnt2) ? csr[rid2 * CAP + lane] : 0;
      di2 = dinv[rid2];
    }
    GATHER8()
    if (g == 0) {
      float* po = out + (((size_t)rid) << 6) + (li << 3);
      float4 o0, o1;
      o0.x = di * a0; o0.y = di * a1; o0.z = di * a2; o0.w = di * a3;
      o1.x = di * a4; o1.y = di * a5; o1.z = di * a6; o1.w = di * a7;
      *(float4*)po = o0;
      *(float4*)(po + 4) = o1;
    }
    if (!have_next) break;
    i = inext; rid = rid2; cnt = cnt2; colv = colv2; di = di2;
  }
}

extern "C" void kernel_launch(void* const* d_in, const int* in_sizes, int n_in,
                              void* d_out, int out_size, void* d_ws, size_t ws_size,
                              hipStream_t stream) {
  const float* x   = (const float*)d_in[0];
  const int*   ei  = (const int*)d_in[1];
  const void*  msk = d_in[2];
  const int N = in_sizes[2];
  const int E = in_sizes[1] / 2;
  const int* row = ei;
  const int* col = ei + E;

  // Pick CAP (slots per row) from available workspace; degree ~ Poisson(16).
  size_t fixedBytes = 2 * (((size_t)N * 64 * 2 + 255) & ~(size_t)255)   // b0,b1
                    + 4 * (((size_t)N * 4 + 255) & ~(size_t)255)        // degc,dinv,cursor,wlist
                    + 1024;                                             // flag + n_un pads
  int CAP = 64;
  if (fixedBytes + (size_t)N * 64 * 4 > ws_size) CAP = 48;
  if (CAP == 48 && fixedBytes + (size_t)N * 48 * 4 > ws_size) CAP = 32;

  char* p = (char*)d_ws;
  auto alloc = [&](size_t bytes) -> char* {
    char* r = p;
    p += (bytes + 255) & ~(size_t)255;
    return r;
  };
  bf16_t* b0     = (bf16_t*)alloc((size_t)N * 64 * 2);
  bf16_t* b1     = (bf16_t*)alloc((size_t)N * 64 * 2);
  int*    degc   = (int*)alloc((size_t)N * 4);
  float*  dinv   = (float*)alloc((size_t)N * 4);
  int*    cursor = (int*)alloc((size_t)N * 4);
  int*    wlist  = (int*)alloc((size_t)N * 4);
  int*    flag   = (int*)alloc(256);
  int*    n_un   = (int*)alloc(256);
  int*    csr    = (int*)alloc((size_t)N * CAP * 4);
  (void)n_in; (void)out_size;

  hipMemsetAsync(degc, 0, (size_t)N * 4, stream);
  hipMemsetAsync(cursor, 0, (size_t)N * 4, stream);
  hipMemsetAsync(n_un, 0, 4, stream);

  const int tb = 256;
  k_detect_mask<<<1, 1024, 0, stream>>>((const uint8_t*)msk, N, flag);
  k_fused_preproc<<<(E + tb - 1) / tb, tb, 0, stream>>>(row, col, E, msk, flag, CAP,
                                                        degc, cursor, csr);
  k_dinv_wlist<<<(N + tb - 1) / tb, tb, 0, stream>>>(degc, dinv, msk, flag, wlist, n_un, N);

  int totalElems = N * 64;
  k_init_state<<<(totalElems + tb - 1) / tb, tb, 0, stream>>>(x, dinv, msk, flag, b0, b1,
                                                              (float*)d_out, totalElems);

  // Persistent grid: 2048 blocks x 4 waves = 8192 waves (~6 rows/wave @ ~50k).
  const int PB = 2048;
  bf16_t* a = b0;
  bf16_t* b = b1;
  for (int it = 0; it < 9; ++it) {
    k_spmm_mid<<<PB, tb, 0, stream>>>(wlist, n_un, csr, cursor, CAP, a, dinv, b);
    bf16_t* t = a; a = b; b = t;
  }
  k_spmm_fin<<<PB, tb, 0, stream>>>(wlist, n_un, csr, cursor, CAP, a, dinv,
                                    (float*)d_out);
}

// Round 14
// 376.738 us; speedup vs baseline: 1.1614x; 1.1614x over previous
//
#include <hip/hip_runtime.h>
#include <stdint.h>

// FeaturePropagator: 10 iters of out = mask ? x : (D^-1/2 A D^-1/2) @ out
// N=100000, E=1600000, D=64.
//
// Scaled-state: s_hat = D^-1/2 s => s_hat'[i] = dinv[i]^2 * sum_{row_e=i} s_hat[col_e];
// final out[i] = dinv[i] * sum. State bf16. CSR = slot array csr[r*CAP+k] (one
// fused atomic edge pass). SpMM: persistent waves over a worklist of unmasked
// rows; 8 groups x 8 lanes; cross-row meta prefetch + 2-deep gather pipeline.
// (Round-12 measured-best structure; round-13's flat GATHER8 regressed: with
// cnt~16 only 2/8 trips valid -> 4x wasted unpack VALU, no extra MLP.)

typedef unsigned short bf16_t;
typedef unsigned int u32;

__device__ __forceinline__ float bf2f(u32 u) {  // low 16 bits = bf16
  union { u32 i; float f; } v;
  v.i = u << 16;
  return v.f;
}
__device__ __forceinline__ u32 f2bf(float f) {  // RNE, returns low16
  union { float f; u32 i; } v;
  v.f = f;
  u32 u = v.i;
  return (u + 0x7FFFu + ((u >> 16) & 1u)) >> 16;
}

__device__ __forceinline__ bool mask_at(const void* m, int i, int byteFlag) {
  return byteFlag ? (((const uint8_t*)m)[i] != 0) : (((const int*)m)[i] != 0);
}

// Parallel detection: is mask 1-byte bool or 4-byte int32? One block.
__global__ void k_detect_mask(const uint8_t* m, int n, int* flag) {
  __shared__ int isByte, anyAligned;
  if (threadIdx.x == 0) { isByte = 0; anyAligned = 0; }
  __syncthreads();
  int nb = n < 4096 ? n : 4096;
  for (int i = threadIdx.x; i < nb; i += blockDim.x) {
    uint8_t v = m[i];
    if (v) {
      if (i & 3) atomicOr(&isByte, 1);
      else       atomicOr(&anyAligned, 1);
    }
  }
  __syncthreads();
  if (threadIdx.x == 0) *flag = (isByte || !anyAligned) ? 1 : 0;
}

// ONE pass over edges: in-degree over col + slot-scatter of unmasked-row edges.
__global__ void k_fused_preproc(const int* __restrict__ row, const int* __restrict__ col,
                                int E, const void* __restrict__ mask,
                                const int* __restrict__ flag, int CAP,
                                int* __restrict__ deg_col, int* __restrict__ cursor,
                                int* __restrict__ csr) {
  int e = blockIdx.x * blockDim.x + threadIdx.x;
  if (e >= E) return;
  int fl = *flag;
  int r = row[e], c = col[e];
  atomicAdd(&deg_col[c], 1);
  if (!mask_at(mask, r, fl)) {
    int pos = atomicAdd(&cursor[r], 1);
    if (pos < CAP) csr[r * CAP + pos] = c;  // overflow beyond CAP dropped (p ~ 1e-15 @64)
  }
}

// dinv + compacted worklist of unmasked rows (order nondeterministic; output
// is order-independent since each row writes only its own dst slice).
__global__ void k_dinv_wlist(const int* __restrict__ deg_col, float* __restrict__ dinv,
                             const void* __restrict__ mask, const int* __restrict__ flag,
                             int* __restrict__ wlist, int* __restrict__ n_un, int N) {
  int i = blockIdx.x * blockDim.x + threadIdx.x;
  if (i >= N) return;
  int d = deg_col[i];
  dinv[i] = d > 0 ? rsqrtf((float)d) : 0.0f;
  if (!mask_at(mask, i, *flag)) {
    int pos = atomicAdd(n_un, 1);  // compiler wave-aggregates
    wlist[pos] = i;
  }
}

// Init: masked rows -> b0=b1=bf16(dinv*x) AND out=x (final value, never
// rewritten); unmasked rows -> b0=0 (iteration-0 state).
__global__ void k_init_state(const float* __restrict__ x, const float* __restrict__ dinv,
                             const void* __restrict__ mask, const int* __restrict__ flag,
                             bf16_t* __restrict__ b0, bf16_t* __restrict__ b1,
                             float* __restrict__ out, int total) {
  int i = blockIdx.x * blockDim.x + threadIdx.x;
  if (i >= total) return;
  int n = i >> 6;  // D == 64
  if (mask_at(mask, n, *flag)) {
    float xv = x[i];
    bf16_t v = (bf16_t)f2bf(dinv[n] * xv);
    b0[i] = v;
    b1[i] = v;
    out[i] = xv;
  } else {
    b0[i] = 0;
  }
}

// Row body shared by mid/fin: 2-deep pipelined gather + reduce. Produces
// reduced a0..a7 (valid in g==0 lanes). Needs lane,g,li,cnt,craw,src in scope.
#define ROW_GATHER_REDUCE()                                                        \
  int colv = (lane < cnt) ? craw : 0;                                              \
  float a0 = 0.f, a1 = 0.f, a2 = 0.f, a3 = 0.f,                                    \
        a4 = 0.f, a5 = 0.f, a6 = 0.f, a7 = 0.f;                                    \
  int kmax = (cnt + 7) >> 3;                                                       \
  uint4 vc = make_uint4(0, 0, 0, 0);                                               \
  {                                                                                \
    int c0 = __shfl(colv, g, 64);                                                  \
    if (g < cnt)                                                                   \
      vc = *(const uint4*)(src + (((size_t)c0) << 6) + (li << 3));                 \
  }                                                                                \
  for (int k = 0; k < kmax; ++k) {                                                 \
    uint4 vn = make_uint4(0, 0, 0, 0);                                             \
    int ei_n = ((k + 1) << 3) + g;                                                 \
    int c_n = __shfl(colv, ei_n & 63, 64);                                         \
    if (k + 1 < kmax && ei_n < cnt)                                                \
      vn = *(const uint4*)(src + (((size_t)c_n) << 6) + (li << 3));                \
    a0 += bf2f(vc.x & 0xffffu); a1 += bf2f(vc.x >> 16);                            \
    a2 += bf2f(vc.y & 0xffffu); a3 += bf2f(vc.y >> 16);                            \
    a4 += bf2f(vc.z & 0xffffu); a5 += bf2f(vc.z >> 16);                            \
    a6 += bf2f(vc.w & 0xffffu); a7 += bf2f(vc.w >> 16);                            \
    vc = vn;                                                                       \
  }                                                                                \
  a0 += __shfl_xor(a0, 8, 64); a0 += __shfl_xor(a0, 16, 64); a0 += __shfl_xor(a0, 32, 64); \
  a1 += __shfl_xor(a1, 8, 64); a1 += __shfl_xor(a1, 16, 64); a1 += __shfl_xor(a1, 32, 64); \
  a2 += __shfl_xor(a2, 8, 64); a2 += __shfl_xor(a2, 16, 64); a2 += __shfl_xor(a2, 32, 64); \
  a3 += __shfl_xor(a3, 8, 64); a3 += __shfl_xor(a3, 16, 64); a3 += __shfl_xor(a3, 32, 64); \
  a4 += __shfl_xor(a4, 8, 64); a4 += __shfl_xor(a4, 16, 64); a4 += __shfl_xor(a4, 32, 64); \
  a5 += __shfl_xor(a5, 8, 64); a5 += __shfl_xor(a5, 16, 64); a5 += __shfl_xor(a5, 32, 64); \
  a6 += __shfl_xor(a6, 8, 64); a6 += __shfl_xor(a6, 16, 64); a6 += __shfl_xor(a6, 32, 64); \
  a7 += __shfl_xor(a7, 8, 64); a7 += __shfl_xor(a7, 16, 64); a7 += __shfl_xor(a7, 32, 64);

// Persistent-wave SpMM (bf16 -> bf16). Waves loop over the worklist with
// stride = total waves; next row's meta prefetched during current row.
__global__ void __launch_bounds__(256)
k_spmm_mid(const int* __restrict__ wlist, const int* __restrict__ n_un,
           const int* __restrict__ csr, const int* __restrict__ cursor, int CAP,
           const bf16_t* __restrict__ src, const float* __restrict__ dinv,
           bf16_t* __restrict__ dst) {
  int wpb = blockDim.x >> 6;
  int stride = gridDim.x * wpb;
  int lane = threadIdx.x & 63;
  int g = lane >> 3, li = lane & 7;
  int n = *n_un;
  int i = blockIdx.x * wpb + (threadIdx.x >> 6);
  if (i >= n) return;
  int rid = wlist[i];
  int cnt = cursor[rid]; if (cnt > CAP) cnt = CAP;
  int craw = csr[rid * CAP + lane];
  float di = dinv[rid];
  while (true) {
    int inext = i + stride;
    bool have_next = inext < n;
    int rid2 = 0, cnt2 = 0, craw2 = 0;
    float di2 = 0.f;
    if (have_next) {  // prefetch next row's meta; hides under current row's work
      rid2 = wlist[inext];
      cnt2 = cursor[rid2]; if (cnt2 > CAP) cnt2 = CAP;
      craw2 = csr[rid2 * CAP + lane];
      di2 = dinv[rid2];
    }
    ROW_GATHER_REDUCE()
    if (g == 0) {
      float s = di * di;
      uint4 o;
      o.x = f2bf(s * a0) | (f2bf(s * a1) << 16);
      o.y = f2bf(s * a2) | (f2bf(s * a3) << 16);
      o.z = f2bf(s * a4) | (f2bf(s * a5) << 16);
      o.w = f2bf(s * a6) | (f2bf(s * a7) << 16);
      *(uint4*)(dst + (((size_t)rid) << 6) + (li << 3)) = o;
    }
    if (!have_next) break;
    i = inext; rid = rid2; cnt = cnt2; craw = craw2; di = di2;
  }
}

// Final iteration: bf16 -> fp32 d_out with dinv unscaling (unmasked rows only;
// masked rows were written by k_init_state).
__global__ void __launch_bounds__(256)
k_spmm_fin(const int* __restrict__ wlist, const int* __restrict__ n_un,
           const int* __restrict__ csr, const int* __restrict__ cursor, int CAP,
           const bf16_t* __restrict__ src, const float* __restrict__ dinv,
           float* __restrict__ out) {
  int wpb = blockDim.x >> 6;
  int stride = gridDim.x * wpb;
  int lane = threadIdx.x & 63;
  int g = lane >> 3, li = lane & 7;
  int n = *n_un;
  int i = blockIdx.x * wpb + (threadIdx.x >> 6);
  if (i >= n) return;
  int rid = wlist[i];
  int cnt = cursor[rid]; if (cnt > CAP) cnt = CAP;
  int craw = csr[rid * CAP + lane];
  float di = dinv[rid];
  while (true) {
    int inext = i + stride;
    bool have_next = inext < n;
    int rid2 = 0, cnt2 = 0, craw2 = 0;
    float di2 = 0.f;
    if (have_next) {
      rid2 = wlist[inext];
      cnt2 = cursor[rid2]; if (cnt2 > CAP) cnt2 = CAP;
      craw2 = csr[rid2 * CAP + lane];
      di2 = dinv[rid2];
    }
    ROW_GATHER_REDUCE()
    if (g == 0) {
      float* po = out + (((size_t)rid) << 6) + (li << 3);
      float4 o0, o1;
      o0.x = di * a0; o0.y = di * a1; o0.z = di * a2; o0.w = di * a3;
      o1.x = di * a4; o1.y = di * a5; o1.z = di * a6; o1.w = di * a7;
      *(float4*)po = o0;
      *(float4*)(po + 4) = o1;
    }
    if (!have_next) break;
    i = inext; rid = rid2; cnt = cnt2; craw = craw2; di = di2;
  }
}

extern "C" void kernel_launch(void* const* d_in, const int* in_sizes, int n_in,
                              void* d_out, int out_size, void* d_ws, size_t ws_size,
                              hipStream_t stream) {
  const float* x   = (const float*)d_in[0];
  const int*   ei  = (const int*)d_in[1];
  const void*  msk = d_in[2];
  const int N = in_sizes[2];
  const int E = in_sizes[1] / 2;
  const int* row = ei;
  const int* col = ei + E;

  // Pick CAP (slots per row) from available workspace; degree ~ Poisson(16).
  size_t fixedBytes = 2 * (((size_t)N * 64 * 2 + 255) & ~(size_t)255)   // b0,b1
                    + 4 * (((size_t)N * 4 + 255) & ~(size_t)255)        // degc,dinv,cursor,wlist
                    + 1024;                                             // flag + n_un pads
  int CAP = 64;
  if (fixedBytes + (size_t)N * 64 * 4 > ws_size) CAP = 48;
  if (CAP == 48 && fixedBytes + (size_t)N * 48 * 4 > ws_size) CAP = 32;

  char* p = (char*)d_ws;
  auto alloc = [&](size_t bytes) -> char* {
    char* r = p;
    p += (bytes + 255) & ~(size_t)255;
    return r;
  };
  bf16_t* b0     = (bf16_t*)alloc((size_t)N * 64 * 2);
  bf16_t* b1     = (bf16_t*)alloc((size_t)N * 64 * 2);
  int*    degc   = (int*)alloc((size_t)N * 4);
  float*  dinv   = (float*)alloc((size_t)N * 4);
  int*    cursor = (int*)alloc((size_t)N * 4);
  int*    wlist  = (int*)alloc((size_t)N * 4);
  int*    flag   = (int*)alloc(256);
  int*    n_un   = (int*)alloc(256);
  int*    csr    = (int*)alloc((size_t)N * CAP * 4);
  (void)n_in; (void)out_size;

  hipMemsetAsync(degc, 0, (size_t)N * 4, stream);
  hipMemsetAsync(cursor, 0, (size_t)N * 4, stream);
  hipMemsetAsync(n_un, 0, 4, stream);

  const int tb = 256;
  k_detect_mask<<<1, 1024, 0, stream>>>((const uint8_t*)msk, N, flag);
  k_fused_preproc<<<(E + tb - 1) / tb, tb, 0, stream>>>(row, col, E, msk, flag, CAP,
                                                        degc, cursor, csr);
  k_dinv_wlist<<<(N + tb - 1) / tb, tb, 0, stream>>>(degc, dinv, msk, flag, wlist, n_un, N);

  int totalElems = N * 64;
  k_init_state<<<(totalElems + tb - 1) / tb, tb, 0, stream>>>(x, dinv, msk, flag, b0, b1,
                                                              (float*)d_out, totalElems);

  // Persistent grid: 2048 blocks x 4 waves = 8192 waves (~6 rows/wave @ ~50k).
  const int PB = 2048;
  bf16_t* a = b0;
  bf16_t* b = b1;
  for (int it = 0; it < 9; ++it) {
    k_spmm_mid<<<PB, tb, 0, stream>>>(wlist, n_un, csr, cursor, CAP, a, dinv, b);
    bf16_t* t = a; a = b; b = t;
  }
  k_spmm_fin<<<PB, tb, 0, stream>>>(wlist, n_un, csr, cursor, CAP, a, dinv,
                                    (float*)d_out);
}